// Round 1
// baseline (469.801 us; speedup 1.0000x reference)
//
#include <hip/hip_runtime.h>
#include <hip/hip_bf16.h>

// GCN layer: out = leaky( (adj @ (node @ W^T)) / deg + b )
// Kernel 1: Ht[b][o][j] = sum_f node[b,j,f]*W[o,f]  (bf16, transposed for B-frag reads)
// Kernel 2 (v2): barrier-free, LDS-free. Each wave owns 16 adj rows exclusively:
//   A-frags straight from global fp32 adj (in-register bf16 convert, fused deg),
//   B-frags straight from global bf16 Ht (L2/L3-resident), A prefetched 1 K-tile ahead.

typedef __attribute__((ext_vector_type(8))) short bf16x8;   // 8 bf16 = 4 VGPR (MFMA A/B frag)
typedef __attribute__((ext_vector_type(4))) float f32x4;    // MFMA C/D frag

// fp32 -> bf16 round-to-nearest-even, via integer bit math
__device__ __forceinline__ unsigned f2bf(float x) {
  unsigned u = __builtin_bit_cast(unsigned, x);
  u += 0x7FFFu + ((u >> 16) & 1u);
  return u >> 16;
}
__device__ __forceinline__ int f2bf2(float x, float y) {
  return (int)(f2bf(x) | (f2bf(y) << 16));
}

#define JPAD 136   // 128 + 8 bf16 pad: row stride 272B -> 2-way LDS aliasing (free)

// ---------------- Kernel 1: Ht = (node @ W^T)^T in bf16 ----------------
__global__ __launch_bounds__(256) void k_ht(const float* __restrict__ node,
                                            const float* __restrict__ W,
                                            ushort* __restrict__ Ht) {
  __shared__ short nt[128 * JPAD];  // node tile [j][f]; reused as [o][j] out-staging
  __shared__ short wt[128 * JPAD];  // W [o][f] bf16
  const int b = blockIdx.y, jt = blockIdx.x, t = threadIdx.x;
  const float4* nbase = (const float4*)(node + (size_t)(b * 1024 + jt * 128) * 128);
  const float4* wbase = (const float4*)W;

  // stage node tile (128x128 f32) + W, converting to bf16
  #pragma unroll
  for (int p = 0; p < 16; p++) {
    int idx = t + 256 * p;
    int r = idx >> 5, c4 = idx & 31;
    float4 v = nbase[idx];
    int2 s; s.x = f2bf2(v.x, v.y); s.y = f2bf2(v.z, v.w);
    *(int2*)&nt[r * JPAD + c4 * 4] = s;
    float4 wv = wbase[idx];
    int2 sw; sw.x = f2bf2(wv.x, wv.y); sw.y = f2bf2(wv.z, wv.w);
    *(int2*)&wt[r * JPAD + c4 * 4] = sw;
  }
  __syncthreads();

  const int lane = t & 63, wid = t >> 6;
  const int q = lane >> 4, r = lane & 15;
  const int wm = wid & 1, wn = wid >> 1;   // 2x2 waves, 64x64 each
  f32x4 acc[4][4] = {};
  #pragma unroll
  for (int ks = 0; ks < 4; ks++) {        // K = 128 over f, 32/step
    bf16x8 af[4], bg[4];
    #pragma unroll
    for (int mi = 0; mi < 4; mi++)
      af[mi] = *(const bf16x8*)&nt[(wm * 64 + mi * 16 + r) * JPAD + ks * 32 + q * 8];
    #pragma unroll
    for (int ni = 0; ni < 4; ni++)
      bg[ni] = *(const bf16x8*)&wt[(wn * 64 + ni * 16 + r) * JPAD + ks * 32 + q * 8];
    #pragma unroll
    for (int mi = 0; mi < 4; mi++)
      #pragma unroll
      for (int ni = 0; ni < 4; ni++)
        acc[mi][ni] = __builtin_amdgcn_mfma_f32_16x16x32_bf16(af[mi], bg[ni], acc[mi][ni], 0, 0, 0);
  }
  __syncthreads();

  // D[row=4q+v][col=r] -> stage transposed [o][j] in LDS, then coalesced global store
  #pragma unroll
  for (int mi = 0; mi < 4; mi++)
    #pragma unroll
    for (int ni = 0; ni < 4; ni++)
      #pragma unroll
      for (int v = 0; v < 4; v++) {
        int j = wm * 64 + mi * 16 + q * 4 + v;
        int o = wn * 64 + ni * 16 + r;
        nt[o * JPAD + j] = (short)f2bf(acc[mi][ni][v]);
      }
  __syncthreads();
  {
    int o = t >> 1, half = t & 1;
    const int4* src = (const int4*)&nt[o * JPAD + half * 64];
    int4* dst = (int4*)(Ht + (size_t)b * 131072 + (size_t)o * 1024 + jt * 128 + half * 64);
    #pragma unroll
    for (int i = 0; i < 8; i++) dst[i] = src[i];
  }
}

// ---------------- Kernel 2 (v2): out = leaky(adj @ Ht^T / deg + bias) ----------------
// Barrier-free / LDS-free. Grid (16, 64), 256 threads = 4 waves; wave owns rows
// i0..i0+15 (i0 = it*64 + wid*16). A-frags: lane(q,r) reads row i0+r, cols
// kt*64 + ks*32 + q*8 as fp32 -> bf16 in-register, deg fused. B-frags: direct
// 16B global loads from bf16 Ht (per-batch slice 256 KB, L2-resident; 4x wave
// read-amplification is L2 traffic at 34 TB/s, not HBM).
__global__ __launch_bounds__(256) void k_main(const float* __restrict__ adj,
                                              const ushort* __restrict__ Ht,
                                              const float* __restrict__ bias,
                                              float* __restrict__ out) {
  const int b = blockIdx.y, it = blockIdx.x, t = threadIdx.x;
  const int lane = t & 63, wid = t >> 6;
  const int q = lane >> 4, r = lane & 15;
  const int i0 = it * 64 + wid * 16;                       // wave's first row
  const float4* ap = (const float4*)(adj + (size_t)(b * 1024 + i0 + r) * 1024); // lane's adj row
  const int4* hb = (const int4*)(Ht + (size_t)b * 131072) + r * 128;            // + o-row r

  f32x4 acc[8] = {};
  float rs = 0.f;

  // prologue: A for kt=0 (2 float4 per ks-half)
  float4 a0 = ap[q * 2], a1 = ap[q * 2 + 1], a2 = ap[q * 2 + 8], a3 = ap[q * 2 + 9];

  #pragma unroll 1
  for (int kt = 0; kt < 16; kt++) {
    // B-frags ks=0: issued first so L2 latency hides under convert + A-prefetch
    int4 bv[8];
    #pragma unroll
    for (int ni = 0; ni < 8; ni++) bv[ni] = hb[ni * 2048 + kt * 8 + q];

    // convert current A tile to bf16 frags; fuse deg partial sums (fp32, matches ref)
    union { bf16x8 v; int i[4]; } u0, u1;
    u0.i[0] = f2bf2(a0.x, a0.y); u0.i[1] = f2bf2(a0.z, a0.w);
    u0.i[2] = f2bf2(a1.x, a1.y); u0.i[3] = f2bf2(a1.z, a1.w);
    u1.i[0] = f2bf2(a2.x, a2.y); u1.i[1] = f2bf2(a2.z, a2.w);
    u1.i[2] = f2bf2(a3.x, a3.y); u1.i[3] = f2bf2(a3.z, a3.w);
    rs += (a0.x + a0.y + a0.z + a0.w) + (a1.x + a1.y + a1.z + a1.w)
        + (a2.x + a2.y + a2.z + a2.w) + (a3.x + a3.y + a3.z + a3.w);

    // prefetch next A tile (HBM latency hides under this iteration's 16 MFMAs)
    const int nb = (kt < 15 ? kt + 1 : 15) * 16 + q * 2;   // kt=15: harmless re-read
    float4 n0 = ap[nb], n1 = ap[nb + 1], n2 = ap[nb + 8], n3 = ap[nb + 9];

    #pragma unroll
    for (int ni = 0; ni < 8; ni++)
      acc[ni] = __builtin_amdgcn_mfma_f32_16x16x32_bf16(
          u0.v, __builtin_bit_cast(bf16x8, bv[ni]), acc[ni], 0, 0, 0);

    // B-frags ks=1: issue under the ks=0 MFMA drain (caps live B regs at ~40)
    #pragma unroll
    for (int ni = 0; ni < 8; ni++) bv[ni] = hb[ni * 2048 + kt * 8 + 4 + q];
    #pragma unroll
    for (int ni = 0; ni < 8; ni++)
      acc[ni] = __builtin_amdgcn_mfma_f32_16x16x32_bf16(
          u1.v, __builtin_bit_cast(bf16x8, bv[ni]), acc[ni], 0, 0, 0);

    a0 = n0; a1 = n1; a2 = n2; a3 = n3;
  }

  // deg: rows are wave-exclusive -> two shuffles finish the reduction (no LDS)
  rs += __shfl_xor(rs, 16);
  rs += __shfl_xor(rs, 32);
  // all lanes with (lane&15)==r now hold deg of row i0+r

  float* obase = out + (size_t)(b * 1024 + i0) * 128;
  #pragma unroll
  for (int v = 0; v < 4; v++) {
    const float rd = 1.0f / __shfl(rs, q * 4 + v);         // deg of row i0 + q*4 + v
    const int i = q * 4 + v;
    #pragma unroll
    for (int ni = 0; ni < 8; ni++) {
      float val = acc[ni][v] * rd + bias[ni * 16 + r];
      val = val >= 0.0f ? val : 0.01f * val;
      obase[(size_t)i * 128 + ni * 16 + r] = val;
    }
  }
}

// ---------------- Fallback (ws too small): straightforward fp32 ----------------
__global__ __launch_bounds__(256) void k_fallback(const float* __restrict__ node,
                                                  const float* __restrict__ adj,
                                                  const float* __restrict__ W,
                                                  const float* __restrict__ bias,
                                                  float* __restrict__ out) {
  __shared__ float red[256];
  __shared__ float agg[128];
  const int b = blockIdx.y, i = blockIdx.x, t = threadIdx.x;
  const float* arow = adj + (size_t)(b * 1024 + i) * 1024;
  float s = 0.f;
  for (int j = t; j < 1024; j += 256) s += arow[j];
  red[t] = s;
  __syncthreads();
  if (t < 128) red[t] += red[t + 128];
  __syncthreads();
  if (t < 64) {
    float v2 = red[t] + red[t + 64];
    #pragma unroll
    for (int off = 32; off; off >>= 1) v2 += __shfl_down(v2, off);
    if (t == 0) red[0] = v2;
  }
  __syncthreads();
  const float rdeg = 1.0f / red[0];
  const int f = t & 127, half = t >> 7;
  const float* nb = node + (size_t)b * 1024 * 128;
  float a = 0.f;
  for (int j = half * 512; j < half * 512 + 512; j++)
    a += arow[j] * nb[(size_t)j * 128 + f];
  __syncthreads();
  if (half == 0) agg[f] = a;
  __syncthreads();
  if (half == 1) agg[f] += a;
  __syncthreads();
  if (t < 128) {
    const float* wr = W + t * 128;
    float o = 0.f;
    for (int f2 = 0; f2 < 128; f2++) o += agg[f2] * wr[f2];
    o = o * rdeg + bias[t];
    out[(size_t)(b * 1024 + i) * 128 + t] = o >= 0.f ? o : 0.01f * o;
  }
}

extern "C" void kernel_launch(void* const* d_in, const int* in_sizes, int n_in,
                              void* d_out, int out_size, void* d_ws, size_t ws_size,
                              hipStream_t stream) {
  const float* node = (const float*)d_in[0];   // [64,1024,128]
  const float* adj  = (const float*)d_in[1];   // [64,1024,1024]
  const float* W    = (const float*)d_in[2];   // [128,128]
  const float* bias = (const float*)d_in[3];   // [128]
  float* out = (float*)d_out;                  // [64,1024,128]
  const size_t ht_bytes = (size_t)64 * 128 * 1024 * 2;  // 16 MiB bf16 Ht
  if (ws_size >= ht_bytes) {
    ushort* Ht = (ushort*)d_ws;
    k_ht<<<dim3(8, 64), 256, 0, stream>>>(node, W, Ht);
    k_main<<<dim3(16, 64), 256, 0, stream>>>(adj, Ht, bias, out);
  } else {
    k_fallback<<<dim3(1024, 64), 256, 0, stream>>>(node, adj, W, bias, out);
  }
}

// Round 2
// 411.931 us; speedup vs baseline: 1.1405x; 1.1405x over previous
//
#include <hip/hip_runtime.h>
#include <hip/hip_bf16.h>

// GCN layer: out = leaky( (adj @ (node @ W^T)) / deg + b )
// Kernel 1: Ht[b][o][j] = sum_f node[b,j,f]*W[o,f]  (bf16, transposed for B-frag reads)
// Kernel 2 (v3): adj per-wave direct from global (read exactly once, fused deg,
//   in-register bf16 convert). Ht staged per K-tile in LDS via global_load_lds
//   (width 16), XOR-swizzled through the pre-swizzled-SOURCE trick (linear LDS
//   dest, permuted global chunk per lane, same XOR on ds_read) -> conflict-min
//   ds_read_b128 B-frags. One barrier per K-tile, double-buffered.

typedef __attribute__((ext_vector_type(8))) short bf16x8;   // 8 bf16 = 4 VGPR (MFMA A/B frag)
typedef __attribute__((ext_vector_type(4))) float f32x4;    // MFMA C/D frag

// fp32 -> bf16 round-to-nearest-even, via integer bit math
__device__ __forceinline__ unsigned f2bf(float x) {
  unsigned u = __builtin_bit_cast(unsigned, x);
  u += 0x7FFFu + ((u >> 16) & 1u);
  return u >> 16;
}
__device__ __forceinline__ int f2bf2(float x, float y) {
  return (int)(f2bf(x) | (f2bf(y) << 16));
}

__device__ __forceinline__ void gload_lds16(const void* g, void* l) {
  __builtin_amdgcn_global_load_lds(
      (const __attribute__((address_space(1))) unsigned int*)g,
      (__attribute__((address_space(3))) unsigned int*)l, 16, 0, 0);
}

#define JPAD 136   // 128 + 8 bf16 pad for k_ht LDS tiles

// ---------------- Kernel 1: Ht = (node @ W^T)^T in bf16 ----------------
__global__ __launch_bounds__(256) void k_ht(const float* __restrict__ node,
                                            const float* __restrict__ W,
                                            ushort* __restrict__ Ht) {
  __shared__ short nt[128 * JPAD];  // node tile [j][f]; reused as [o][j] out-staging
  __shared__ short wt[128 * JPAD];  // W [o][f] bf16
  const int b = blockIdx.y, jt = blockIdx.x, t = threadIdx.x;
  const float4* nbase = (const float4*)(node + (size_t)(b * 1024 + jt * 128) * 128);
  const float4* wbase = (const float4*)W;

  #pragma unroll
  for (int p = 0; p < 16; p++) {
    int idx = t + 256 * p;
    int r = idx >> 5, c4 = idx & 31;
    float4 v = nbase[idx];
    int2 s; s.x = f2bf2(v.x, v.y); s.y = f2bf2(v.z, v.w);
    *(int2*)&nt[r * JPAD + c4 * 4] = s;
    float4 wv = wbase[idx];
    int2 sw; sw.x = f2bf2(wv.x, wv.y); sw.y = f2bf2(wv.z, wv.w);
    *(int2*)&wt[r * JPAD + c4 * 4] = sw;
  }
  __syncthreads();

  const int lane = t & 63, wid = t >> 6;
  const int q = lane >> 4, r = lane & 15;
  const int wm = wid & 1, wn = wid >> 1;   // 2x2 waves, 64x64 each
  f32x4 acc[4][4] = {};
  #pragma unroll
  for (int ks = 0; ks < 4; ks++) {        // K = 128 over f, 32/step
    bf16x8 af[4], bg[4];
    #pragma unroll
    for (int mi = 0; mi < 4; mi++)
      af[mi] = *(const bf16x8*)&nt[(wm * 64 + mi * 16 + r) * JPAD + ks * 32 + q * 8];
    #pragma unroll
    for (int ni = 0; ni < 4; ni++)
      bg[ni] = *(const bf16x8*)&wt[(wn * 64 + ni * 16 + r) * JPAD + ks * 32 + q * 8];
    #pragma unroll
    for (int mi = 0; mi < 4; mi++)
      #pragma unroll
      for (int ni = 0; ni < 4; ni++)
        acc[mi][ni] = __builtin_amdgcn_mfma_f32_16x16x32_bf16(af[mi], bg[ni], acc[mi][ni], 0, 0, 0);
  }
  __syncthreads();

  #pragma unroll
  for (int mi = 0; mi < 4; mi++)
    #pragma unroll
    for (int ni = 0; ni < 4; ni++)
      #pragma unroll
      for (int v = 0; v < 4; v++) {
        int j = wm * 64 + mi * 16 + q * 4 + v;
        int o = wn * 64 + ni * 16 + r;
        nt[o * JPAD + j] = (short)f2bf(acc[mi][ni][v]);
      }
  __syncthreads();
  {
    int o = t >> 1, half = t & 1;
    const int4* src = (const int4*)&nt[o * JPAD + half * 64];
    int4* dst = (int4*)(Ht + (size_t)b * 131072 + (size_t)o * 1024 + jt * 128 + half * 64);
    #pragma unroll
    for (int i = 0; i < 8; i++) dst[i] = src[i];
  }
}

// ---------------- Kernel 2 (v3): out = leaky(adj @ Ht^T / deg + bias) ----------------
// Grid (16, 64), 256 threads = 4 waves; wave owns rows i0..i0+15. Per kt (BK=64):
//   LDS holds Ht[o=0..127][j-slice 64] bf16 = 16 KB, double-buffered.
//   Swizzle: LDS slot (o, s) [s = 16B chunk 0..7] holds global chunk s ^ (o&7).
//   Staged linearly by global_load_lds: wave w, inst p, lane l ->
//   LDS off = (w*32+8p+(l>>3))*128 + (l&7)*16, global chunk (l&7)^((l>>3)&7).
__global__ __launch_bounds__(256) void k_main(const float* __restrict__ adj,
                                              const ushort* __restrict__ Ht,
                                              const float* __restrict__ bias,
                                              float* __restrict__ out) {
  __shared__ short hbuf[2][128 * 64];   // 2 x 16 KB
  const int b = blockIdx.y, it = blockIdx.x, t = threadIdx.x;
  const int lane = t & 63, wid = t >> 6;
  const int q = lane >> 4, r = lane & 15;
  const int i0 = it * 64 + wid * 16;                       // wave's first row
  const float4* ap = (const float4*)(adj + (size_t)(b * 1024 + i0 + r) * 1024); // lane's adj row

  // staging source (per lane, constant across kt): row o = wid*32 + (lane>>3) + 8p
  const int o_l = wid * 32 + (lane >> 3);
  const int cchunk = (lane & 7) ^ ((lane >> 3) & 7);       // inverse-swizzled global chunk
  const ushort* gsrc = Ht + (size_t)b * 131072 + (size_t)o_l * 1024 + cchunk * 8;

  // ds_read byte offsets (per lane): row (ni*16+r), chunk (ks*4+q)^(r&7)
  const int boff0 = r * 128 + (((0 * 4 + q) ^ (r & 7)) << 4);
  const int boff1 = r * 128 + (((1 * 4 + q) ^ (r & 7)) << 4);

  f32x4 acc[8] = {};
  float rs = 0.f;

  // prologue: stage kt=0 into buf0; load A for kt=0
  #pragma unroll
  for (int p = 0; p < 4; p++)
    gload_lds16(gsrc + (size_t)p * 8192, &hbuf[0][(wid * 32 + 8 * p) * 64]);
  float4 a0 = ap[q * 2], a1 = ap[q * 2 + 1], a2 = ap[q * 2 + 8], a3 = ap[q * 2 + 9];
  __syncthreads();   // drains vmcnt(0): buf0 ready

  int c = 0;
  #pragma unroll 1
  for (int kt = 0; kt < 16; kt++) {
    // issue stage of kt+1 into the other buffer (no wait here)
    if (kt < 15) {
      #pragma unroll
      for (int p = 0; p < 4; p++)
        gload_lds16(gsrc + (size_t)p * 8192 + (kt + 1) * 64,
                    &hbuf[c ^ 1][(wid * 32 + 8 * p) * 64]);
    }

    // convert current A tile; fuse deg partial sums (fp32, matches ref)
    union { bf16x8 v; int i[4]; } u0, u1;
    u0.i[0] = f2bf2(a0.x, a0.y); u0.i[1] = f2bf2(a0.z, a0.w);
    u0.i[2] = f2bf2(a1.x, a1.y); u0.i[3] = f2bf2(a1.z, a1.w);
    u1.i[0] = f2bf2(a2.x, a2.y); u1.i[1] = f2bf2(a2.z, a2.w);
    u1.i[2] = f2bf2(a3.x, a3.y); u1.i[3] = f2bf2(a3.z, a3.w);
    rs += (a0.x + a0.y + a0.z + a0.w) + (a1.x + a1.y + a1.z + a1.w)
        + (a2.x + a2.y + a2.z + a2.w) + (a3.x + a3.y + a3.z + a3.w);

    // prefetch next A tile (1-deep; barrier drain at loop end is amortized
    // by the ~5000-cy BW-limited iteration length)
    const int nb = (kt < 15 ? kt + 1 : 15) * 16 + q * 2;
    float4 n0 = ap[nb], n1 = ap[nb + 1], n2 = ap[nb + 8], n3 = ap[nb + 9];

    const char* hb = (const char*)&hbuf[c][0];
    int4 bv[8];
    #pragma unroll
    for (int ni = 0; ni < 8; ni++) bv[ni] = *(const int4*)(hb + boff0 + ni * 2048);
    #pragma unroll
    for (int ni = 0; ni < 8; ni++)
      acc[ni] = __builtin_amdgcn_mfma_f32_16x16x32_bf16(
          u0.v, __builtin_bit_cast(bf16x8, bv[ni]), acc[ni], 0, 0, 0);
    #pragma unroll
    for (int ni = 0; ni < 8; ni++) bv[ni] = *(const int4*)(hb + boff1 + ni * 2048);
    #pragma unroll
    for (int ni = 0; ni < 8; ni++)
      acc[ni] = __builtin_amdgcn_mfma_f32_16x16x32_bf16(
          u1.v, __builtin_bit_cast(bf16x8, bv[ni]), acc[ni], 0, 0, 0);

    a0 = n0; a1 = n1; a2 = n2; a3 = n3;
    __syncthreads();   // kt+1 stage complete; all waves done reading buf[c]
    c ^= 1;
  }

  // deg: rows are wave-exclusive -> two shuffles finish the reduction (no LDS)
  rs += __shfl_xor(rs, 16);
  rs += __shfl_xor(rs, 32);

  float* obase = out + (size_t)(b * 1024 + i0) * 128;
  #pragma unroll
  for (int v = 0; v < 4; v++) {
    const float rd = 1.0f / __shfl(rs, q * 4 + v);         // deg of row i0 + q*4 + v
    const int i = q * 4 + v;
    #pragma unroll
    for (int ni = 0; ni < 8; ni++) {
      float val = acc[ni][v] * rd + bias[ni * 16 + r];
      val = val >= 0.0f ? val : 0.01f * val;
      obase[(size_t)i * 128 + ni * 16 + r] = val;
    }
  }
}

// ---------------- Fallback (ws too small): straightforward fp32 ----------------
__global__ __launch_bounds__(256) void k_fallback(const float* __restrict__ node,
                                                  const float* __restrict__ adj,
                                                  const float* __restrict__ W,
                                                  const float* __restrict__ bias,
                                                  float* __restrict__ out) {
  __shared__ float red[256];
  __shared__ float agg[128];
  const int b = blockIdx.y, i = blockIdx.x, t = threadIdx.x;
  const float* arow = adj + (size_t)(b * 1024 + i) * 1024;
  float s = 0.f;
  for (int j = t; j < 1024; j += 256) s += arow[j];
  red[t] = s;
  __syncthreads();
  if (t < 128) red[t] += red[t + 128];
  __syncthreads();
  if (t < 64) {
    float v2 = red[t] + red[t + 64];
    #pragma unroll
    for (int off = 32; off; off >>= 1) v2 += __shfl_down(v2, off);
    if (t == 0) red[0] = v2;
  }
  __syncthreads();
  const float rdeg = 1.0f / red[0];
  const int f = t & 127, half = t >> 7;
  const float* nb = node + (size_t)b * 1024 * 128;
  float a = 0.f;
  for (int j = half * 512; j < half * 512 + 512; j++)
    a += arow[j] * nb[(size_t)j * 128 + f];
  __syncthreads();
  if (half == 0) agg[f] = a;
  __syncthreads();
  if (half == 1) agg[f] += a;
  __syncthreads();
  if (t < 128) {
    const float* wr = W + t * 128;
    float o = 0.f;
    for (int f2 = 0; f2 < 128; f2++) o += agg[f2] * wr[f2];
    o = o * rdeg + bias[t];
    out[(size_t)(b * 1024 + i) * 128 + t] = o >= 0.f ? o : 0.01f * o;
  }
}

extern "C" void kernel_launch(void* const* d_in, const int* in_sizes, int n_in,
                              void* d_out, int out_size, void* d_ws, size_t ws_size,
                              hipStream_t stream) {
  const float* node = (const float*)d_in[0];   // [64,1024,128]
  const float* adj  = (const float*)d_in[1];   // [64,1024,1024]
  const float* W    = (const float*)d_in[2];   // [128,128]
  const float* bias = (const float*)d_in[3];   // [128]
  float* out = (float*)d_out;                  // [64,1024,128]
  const size_t ht_bytes = (size_t)64 * 128 * 1024 * 2;  // 16 MiB bf16 Ht
  if (ws_size >= ht_bytes) {
    ushort* Ht = (ushort*)d_ws;
    k_ht<<<dim3(8, 64), 256, 0, stream>>>(node, W, Ht);
    k_main<<<dim3(16, 64), 256, 0, stream>>>(adj, Ht, bias, out);
  } else {
    k_fallback<<<dim3(1024, 64), 256, 0, stream>>>(node, adj, W, bias, out);
  }
}